// Round 7
// baseline (1114.810 us; speedup 1.0000x reference)
//
#include <hip/hip_runtime.h>
#include <stdint.h>

// Persistent-kernel RNN: 256 wgs (1/CU), W_hh bf16 resident in LDS (16 j-slices),
// batch split 16 ways; h exchanged via MALL (sc0 sc1), R8 2x2 wave blocking.
// R9: TAG-IN-DATA exchange — no flags, no producer drain, no poison.
//   Evidence: FETCH=0.59 MB/step vs 16 MB/step exchange demand => L2 already
//   absorbs the read amplification (R7 flat, confirmed). The remaining lever is
//   the serialized protocol chain (store drain + flag store + flag visibility +
//   poll detect ~= 3 MALL RTTs/step).
//   Protocol: each 16B h packet (one atomic store16) carries a 1-bit step tag in
//   the LSB of its FIRST bf16: tag = (t>>1)&1. Ping-pong staleness is t vs t-2,
//   and (t>>1)&1 always differs between t and t-2 => consumer validates each
//   packet ((reg.x^tag)&1) and retries until fresh. Producer: store16, done —
//   no drain, no flag, no release barrier. Consumer: issue loads immediately,
//   counted-vmcnt consume, per-chunk validate+retry.
//   Ordering (same induction as R5, minus poison): consumer validates ALL
//   peers' packets each step => peer skew <= 1 step; a producer reaches its
//   step-t store only after observing all h(t-1), which postdates every peer's
//   reads of h(t-2) => ping-pong WAW is transitively ordered. Grounded at t=0.
//   hipMemsetAsync(0xFF) per launch => initial LSB=1 mismatches t=1,2's
//   expected tag 0 (also covers stale data from a previous launch).
//   Numerics: only packet-head halves (1/8 of elements) get LSB forced,
//   <=1 ULP bf16 => absmax ~unchanged.
// Also R9: conflict-free reduction scratch swizzle (off = tid*8 + (tid>>2)*4:
// each 8 lanes cover all 32 banks) — R8's tid*8 layout was a 16-way conflict
// (SQ_LDS_BANK_CONFLICT 786K -> 7.08M).

#define BATCH 512
#define SEQ   256
#define HID   1024
#define CLS   128

#define GB 16          // batch groups
#define GJ 16          // hidden slices
#define BT 32          // batch rows per wg
#define JT 64          // hidden cols per wg
#define KC 256         // k-chunk per stage buffer fill
#define WSTR 1028      // W LDS row stride (halves): 2-way banks, 8B aligned
#define SSTR 260       // stage row stride (halves)
#define HSTR 68        // h-store exchange row stride (halves)
#define SMEM_BYTES ((JT * WSTR + BT * SSTR) * 2)   // 148224 B
#define HBUF_HALVES (BATCH * HID)                  // 1 MB per buffer
#define RED_OFF 2176   // halves: acc-reduction scratch at sS+4352 B (above hS)

typedef __attribute__((ext_vector_type(8))) short  bf16x8;
typedef __attribute__((ext_vector_type(4))) short  s16x4;
typedef __attribute__((ext_vector_type(4))) float  f32x4;
typedef __attribute__((ext_vector_type(4))) int    i32x4;
typedef __attribute__((ext_vector_type(2))) unsigned int u32x2;

__device__ __forceinline__ unsigned short f2bf(float f) {
  unsigned int u = __float_as_uint(f);
  u = (u + 0x7FFFu + ((u >> 16) & 1u)) >> 16;   // RNE
  return (unsigned short)u;
}
__device__ __forceinline__ float b2f(short h) {
  return __uint_as_float(((unsigned int)(unsigned short)h) << 16);
}

// ---- device-coherent (MALL) accesses ----
__device__ __forceinline__ void store16(void* p, i32x4 v) {
  asm volatile("global_store_dwordx4 %0, %1, off sc0 sc1" :: "v"(p), "v"(v) : "memory");
}
__device__ __forceinline__ void waitcnt0() {
  asm volatile("s_waitcnt vmcnt(0)" ::: "memory");
}
// raw workgroup barrier: drains LDS ops only — global loads/stores stay in flight
__device__ __forceinline__ void barrier_lgkm() {
  asm volatile("s_waitcnt lgkmcnt(0)\n\ts_barrier" ::: "memory");
}
// issue 4x dwordx4 coherent loads (64 B/thread), no wait
__device__ __forceinline__ void issue4(const void* p, i32x4& a, i32x4& b, i32x4& c, i32x4& d) {
  asm volatile(
    "global_load_dwordx4 %0, %4, off sc0 sc1\n\t"
    "global_load_dwordx4 %1, %4, off offset:128 sc0 sc1\n\t"
    "global_load_dwordx4 %2, %4, off offset:256 sc0 sc1\n\t"
    "global_load_dwordx4 %3, %4, off offset:384 sc0 sc1"
    : "=&v"(a), "=&v"(b), "=&v"(c), "=&v"(d)
    : "v"(p) : "memory");
}
// counted waits, tying the chunk's registers so LDS writes can't be hoisted.
// vmcnt(N): everything except the youngest N ops is done (in-order retirement).
// Our step-t-1 h-stores are OLDER than these loads, so they ack first — the
// counted waits stay exact even with stores still nominally in flight.
#define DEF_WAIT(NAME, N) \
__device__ __forceinline__ void NAME(i32x4& a, i32x4& b, i32x4& c, i32x4& d) { \
  asm volatile("s_waitcnt vmcnt(" #N ")" : "+v"(a), "+v"(b), "+v"(c), "+v"(d) :: "memory"); \
}
DEF_WAIT(wait_vm12, 12)
DEF_WAIT(wait_vm8, 8)
DEF_WAIT(wait_vm4, 4)
DEF_WAIT(wait_vm0, 0)

__device__ __forceinline__ void wr16(short* p, i32x4 v) {  // 16 B to LDS as 2x b64
  u32x2 lo, hi;
  lo.x = (unsigned)v.x; lo.y = (unsigned)v.y;
  hi.x = (unsigned)v.z; hi.y = (unsigned)v.w;
  *(u32x2*)p = lo;
  *(u32x2*)(p + 4) = hi;
}
__device__ __forceinline__ bf16x8 ld8(const short* p) {    // 8 bf16 from LDS as 2x b64
  union { bf16x8 v8; s16x4 h[2]; } u;
  u.h[0] = *(const s16x4*)p;
  u.h[1] = *(const s16x4*)(p + 4);
  return u.v8;
}
__device__ __forceinline__ float tanh_fast(float z) {
  float e = __expf(2.f * z);
  return 1.f - 2.f / (e + 1.f);
}

// TAG validation: each 16B packet is one atomic store16; its first bf16's LSB
// carries (t>>1)&1. Stale ping-pong content is from step t-2, whose tag always
// differs. Check only .x (the packet head dword's low half).
__device__ __forceinline__ bool stale4(const i32x4& a, const i32x4& b,
                                       const i32x4& c, const i32x4& d, int tg) {
  return ((((a.x ^ tg) | (b.x ^ tg) | (c.x ^ tg) | (d.x ^ tg)) & 1)) != 0;
}
__device__ __forceinline__ void retry4(const void* p, i32x4& a, i32x4& b,
                                       i32x4& c, i32x4& d, int tg) {
  do {
    asm volatile("s_sleep 2" ::: "memory");
    issue4(p, a, b, c, d);
    waitcnt0();
  } while (stale4(a, b, c, d, tg));
}

// 2x2 block, k-half per wave pair: 16 ld8 (32 b64) for 16 MFMAs per chunk.
__device__ __forceinline__ void mfma_chunk22(const short* sW, const short* sS,
                                             int cp, int kh, int l15, int quad, int c,
                                             f32x4& a00, f32x4& a01,
                                             f32x4& a10, f32x4& a11) {
  const short* B0  = sW + (cp * 32 + l15) * WSTR + c * KC + kh * 128 + quad * 8;
  const short* B1  = B0 + 16 * WSTR;
  const short* Ar0 = sS + l15 * SSTR + kh * 128 + quad * 8;
  const short* Ar1 = Ar0 + 16 * SSTR;
#pragma unroll
  for (int i = 0; i < 4; ++i) {
    bf16x8 b0 = ld8(B0  + i * 32);
    bf16x8 b1 = ld8(B1  + i * 32);
    bf16x8 a0 = ld8(Ar0 + i * 32);
    bf16x8 a1 = ld8(Ar1 + i * 32);
    a00 = __builtin_amdgcn_mfma_f32_16x16x32_bf16(a0, b0, a00, 0, 0, 0);
    a10 = __builtin_amdgcn_mfma_f32_16x16x32_bf16(a1, b0, a10, 0, 0, 0);
    a01 = __builtin_amdgcn_mfma_f32_16x16x32_bf16(a0, b1, a01, 0, 0, 0);
    a11 = __builtin_amdgcn_mfma_f32_16x16x32_bf16(a1, b1, a11, 0, 0, 0);
  }
}

__global__ void __launch_bounds__(256, 1)
rnn_persistent(const float* __restrict__ x, const float* __restrict__ Whx,
               const float* __restrict__ Whh, const float* __restrict__ bh,
               const float* __restrict__ Wph, const float* __restrict__ bp,
               float* __restrict__ out, unsigned short* hbuf)
{
  extern __shared__ short smem[];
  short* sW = smem;                 // [JT][WSTR] bf16 W_hh slice, persistent
  short* sS = smem + JT * WSTR;     // [BT][SSTR] bf16 h k-chunk stage (+ hS/red overlay)

  const int tid  = threadIdx.x;
  const int bg   = blockIdx.x & 15;
  const int jg   = blockIdx.x >> 4;
  const int lane = tid & 63;
  const int wv   = tid >> 6;
  const int l15  = lane & 15;
  const int quad = lane >> 4;
  const int cp   = wv & 1;          // col-pair: this wave's cols = cp*32 .. +32
  const int kh   = wv >> 1;         // k-half within each chunk: ks = kh*4 .. +4

  // ---- stage W_hh[jg*64 .. +64)[0..1024) into LDS as bf16 ----
  {
    const int jr = tid >> 2;
    const int kq = tid & 3;
    const float* src = Whh + (jg * JT + jr) * HID + kq * 256;
    short* dst = sW + jr * WSTR + kq * 256;
#pragma unroll 4
    for (int i = 0; i < 64; ++i) {
      float4 f = *(const float4*)(src + i * 4);
      s16x4 h4;
      h4.x = (short)f2bf(f.x); h4.y = (short)f2bf(f.y);
      h4.z = (short)f2bf(f.z); h4.w = (short)f2bf(f.w);
      *(s16x4*)(dst + i * 4) = h4;
    }
  }

  // per-lane output columns (two tiles: ct=0,1 at cp*32 + ct*16 + l15)
  const int j0 = jg * JT + cp * 32 + l15;
  const int j1 = j0 + 16;
  const float whx0 = Whx[j0], whx1 = Whx[j1];
  const float bhv0 = bh[j0],  bhv1 = bh[j1];
  const int grow0 = bg * BT + quad * 4;        // batch row base (row-block 0)
  const int tagger = (l15 & 7) == 0;           // this lane's cols are packet heads

  // staging thread mapping: 64 B per thread per chunk
  const int sr  = tid >> 3;               // 0..31 stage row
  const int seg = tid & 7;                // 0..7

  // conflict-free reduction scratch offsets (dwords): 8 lanes cover 32 banks
  const int roff  = tid * 8 + (tid >> 2) * 4;
  const int ptid  = tid ^ 128;            // k-partner wave (wv^2), same lane
  const int proff = ptid * 8 + (ptid >> 2) * 4;

  for (int t = 0; t < SEQ; ++t) {
    const unsigned short* hin = hbuf + ((t + 1) & 1) * HBUF_HALVES;
    unsigned short*      hout = hbuf + (t & 1) * HBUF_HALVES;
    const int tg_w = (t >> 1) & 1;
    const int tg_r = ((t - 1) >> 1) & 1;

    f32x4 acc00 = {0.f, 0.f, 0.f, 0.f};
    f32x4 acc01 = {0.f, 0.f, 0.f, 0.f};
    f32x4 acc10 = {0.f, 0.f, 0.f, 0.f};
    f32x4 acc11 = {0.f, 0.f, 0.f, 0.f};

    // x for this step — plain loads, older than the staging loads (in-order
    // retirement keeps the counted vmcnt waits below exact).
    float xv0[4], xv1[4];
    {
      const float* xp = x + grow0 * SEQ + t;
#pragma unroll
      for (int rg = 0; rg < 4; ++rg) {
        xv0[rg] = xp[rg * SEQ];
        xv1[rg] = xp[(16 + rg) * SEQ];
      }
    }

    if (t > 0) {
      const char* lbase = (const char*)(hin + (bg * BT + sr) * HID) + seg * 16;
      short* sdst = sS + sr * SSTR + seg * 8;

      i32x4 a0, a1, a2, a3, b0, b1, b2, b3, c0, c1, c2, c3, d0, d1, d2, d3;
      issue4(lbase,        a0, a1, a2, a3);   // chunk 0
      issue4(lbase + 512,  b0, b1, b2, b3);   // chunk 1
      issue4(lbase + 1024, c0, c1, c2, c3);   // chunk 2
      issue4(lbase + 1536, d0, d1, d2, d3);   // chunk 3

      // chunk 0 — on stale (peers lagging) retry ALL chunks together
      wait_vm12(a0, a1, a2, a3);
      if (__builtin_expect(stale4(a0, a1, a2, a3, tg_r), 0)) {
        waitcnt0();
        do {
          asm volatile("s_sleep 2" ::: "memory");
          issue4(lbase,        a0, a1, a2, a3);
          issue4(lbase + 512,  b0, b1, b2, b3);
          issue4(lbase + 1024, c0, c1, c2, c3);
          issue4(lbase + 1536, d0, d1, d2, d3);
          waitcnt0();
        } while (stale4(a0, a1, a2, a3, tg_r));
      }
      wr16(sdst, a0); wr16(sdst + 64, a1); wr16(sdst + 128, a2); wr16(sdst + 192, a3);
      barrier_lgkm();
      mfma_chunk22(sW, sS, cp, kh, l15, quad, 0, acc00, acc01, acc10, acc11);

      // chunk 1
      barrier_lgkm();                          // all waves done reading chunk 0
      wait_vm8(b0, b1, b2, b3);
      if (__builtin_expect(stale4(b0, b1, b2, b3, tg_r), 0)) {
        waitcnt0(); retry4(lbase + 512, b0, b1, b2, b3, tg_r);
      }
      wr16(sdst, b0); wr16(sdst + 64, b1); wr16(sdst + 128, b2); wr16(sdst + 192, b3);
      barrier_lgkm();
      mfma_chunk22(sW, sS, cp, kh, l15, quad, 1, acc00, acc01, acc10, acc11);

      // chunk 2
      barrier_lgkm();
      wait_vm4(c0, c1, c2, c3);
      if (__builtin_expect(stale4(c0, c1, c2, c3, tg_r), 0)) {
        waitcnt0(); retry4(lbase + 1024, c0, c1, c2, c3, tg_r);
      }
      wr16(sdst, c0); wr16(sdst + 64, c1); wr16(sdst + 128, c2); wr16(sdst + 192, c3);
      barrier_lgkm();
      mfma_chunk22(sW, sS, cp, kh, l15, quad, 2, acc00, acc01, acc10, acc11);

      // chunk 3
      barrier_lgkm();
      wait_vm0(d0, d1, d2, d3);
      if (__builtin_expect(stale4(d0, d1, d2, d3, tg_r), 0)) {
        retry4(lbase + 1536, d0, d1, d2, d3, tg_r);
      }
      wr16(sdst, d0); wr16(sdst + 64, d1); wr16(sdst + 128, d2); wr16(sdst + 192, d3);
      barrier_lgkm();
      mfma_chunk22(sW, sS, cp, kh, l15, quad, 3, acc00, acc01, acc10, acc11);
    }

    // ---- k-pair reduction (swizzled scratch), tanh, tag, LDS exchange ----
    barrier_lgkm();     // chunk-3 stage reads done everywhere (sS reusable)
    {
      // write the two accs this wave does NOT finish (the other row-block)
      float* red = (float*)(sS + RED_OFF);
      f32x4 w0 = kh ? acc00 : acc10;
      f32x4 w1 = kh ? acc01 : acc11;
      *(f32x4*)(red + roff)     = w0;
      *(f32x4*)(red + roff + 4) = w1;
    }
    barrier_lgkm();
    {
      const float* red = (const float*)(sS + RED_OFF);
      f32x4 r0 = *(const f32x4*)(red + proff);
      f32x4 r1 = *(const f32x4*)(red + proff + 4);
      f32x4 f0 = (kh ? acc10 : acc00) + r0;
      f32x4 f1 = (kh ? acc11 : acc01) + r1;

      // h = tanh(acc + x*whx + bh) into hS; packet-head lanes carry the tag
      short* hS = sS;   // [BT][HSTR] overlay (disjoint from red: hS < 4352 B)
      const int rbase = kh * 16 + quad * 4;
#pragma unroll
      for (int rg = 0; rg < 4; ++rg) {
        float xr = kh ? xv1[rg] : xv0[rg];
        unsigned short v0 = f2bf(tanh_fast(f0[rg] + xr * whx0 + bhv0));
        unsigned short v1 = f2bf(tanh_fast(f1[rg] + xr * whx1 + bhv1));
        if (tagger) {
          v0 = (unsigned short)((v0 & 0xFFFEu) | (unsigned)tg_w);
          v1 = (unsigned short)((v1 & 0xFFFEu) | (unsigned)tg_w);
        }
        hS[(rbase + rg) * HSTR + cp * 32 + l15]      = (short)v0;
        hS[(rbase + rg) * HSTR + cp * 32 + 16 + l15] = (short)v1;
      }
    }
    barrier_lgkm();
    {
      const short* hsrc = sS + sr * HSTR + seg * 8;
      u32x2 lo = *(const u32x2*)(hsrc);
      u32x2 hi = *(const u32x2*)(hsrc + 4);
      i32x4 sv; sv.x = (int)lo.x; sv.y = (int)lo.y; sv.z = (int)hi.x; sv.w = (int)hi.y;
      unsigned short* dst = hout + (bg * BT + sr) * HID + jg * JT + seg * 8;
      store16(dst, sv);   // release: no drain, no flag — the tag IS the flag
    }
    barrier_lgkm();       // LDS-exchange reads done before next-step sS reuse
  }

  // ---- output head: out[b, jg*8+cc] = h_last . W_ph[c] + b_p ----
  const unsigned short* hlast = hbuf + ((SEQ - 1) & 1) * HBUF_HALVES;
  const int tg_l = ((SEQ - 1) >> 1) & 1;   // = 1
  const int cc = tid & 7;
  const int cg = jg * 8 + cc;
  const int hr = tid >> 3;
  float acc = 0.f;
  const char* lbase = (const char*)(hlast + (bg * BT + sr) * HID) + seg * 16;
  short* sdst = sS + sr * SSTR + seg * 8;
  for (int c = 0; c < 4; ++c) {
    __syncthreads();
    i32x4 p0, p1, p2, p3;
    issue4(lbase + c * 512, p0, p1, p2, p3);
    waitcnt0();
    if (stale4(p0, p1, p2, p3, tg_l)) retry4(lbase + c * 512, p0, p1, p2, p3, tg_l);
    wr16(sdst, p0); wr16(sdst + 64, p1); wr16(sdst + 128, p2); wr16(sdst + 192, p3);
    __syncthreads();
    const float* wp = Wph + cg * HID + c * KC;
    const short* hs = sS + hr * SSTR;
#pragma unroll 8
    for (int k4 = 0; k4 < 64; ++k4) {
      float4 w  = *(const float4*)(wp + k4 * 4);
      s16x4 hv  = *(const s16x4*)(hs + k4 * 4);
      acc += b2f(hv.x) * w.x + b2f(hv.y) * w.y + b2f(hv.z) * w.z + b2f(hv.w) * w.w;
    }
  }
  out[(bg * BT + hr) * CLS + cg] = acc + bp[cg];
}

extern "C" void kernel_launch(void* const* d_in, const int* in_sizes, int n_in,
                              void* d_out, int out_size, void* d_ws, size_t ws_size,
                              hipStream_t stream) {
  const float* x   = (const float*)d_in[0];
  const float* Whx = (const float*)d_in[1];
  const float* Whh = (const float*)d_in[2];
  const float* bh  = (const float*)d_in[3];
  const float* Wph = (const float*)d_in[4];
  const float* bp  = (const float*)d_in[5];
  float* out = (float*)d_out;

  unsigned short* hbuf = (unsigned short*)d_ws;

  // Re-tag both ping-pong buffers each launch: 0xFF halves have LSB=1, which
  // mismatches t=1,2's expected tag 0 — covers first launch, graph replay, and
  // stale data from a previous run (whose final tags would otherwise collide).
  hipMemsetAsync(d_ws, 0xFF, (size_t)2 * HBUF_HALVES * 2, stream);

  hipFuncSetAttribute(reinterpret_cast<const void*>(rnn_persistent),
                      hipFuncAttributeMaxDynamicSharedMemorySize, SMEM_BYTES);

  rnn_persistent<<<dim3(GB * GJ), dim3(256), SMEM_BYTES, stream>>>(
      x, Whx, Whh, bh, Wph, bp, out, hbuf);
}